// Round 9
// baseline (87.514 us; speedup 1.0000x reference)
//
#include <hip/hip_runtime.h>

constexpr int Cc   = 224;            // channels
constexpr int Tt   = 224;            // time steps
constexpr int TT   = 32;             // time tile
constexpr int NT   = Tt / TT;        // 7
constexpr int LDW  = 36;             // words per LDS row (144 B) -> b128 bank-balanced
constexpr int ROWS = 236;            // row r <-> channel r-6; rows 0..5,230..235 zero halo
constexpr int BUFW = ROWS * LDW;     // 8496 words per buffer
constexpr int BDIM = 256;

__global__ __launch_bounds__(BDIM, 2)
void cgss_snn_kernel(const float* __restrict__ x,
                     const float* __restrict__ wp,
                     float* __restrict__ out)
{
    __shared__ float lds[2 * BUFW];      // 67968 B
    __shared__ unsigned msk[2 * 256];    // parity-banked per-tile spike masks

    const int tid = threadIdx.x;
    const int w   = tid >> 6;        // wave 0..3
    const int l   = tid & 63;
    const long long bofs = (long long)blockIdx.x * (Cc * Tt);
    const float* xb = x + bofs;
    float*       ob = out + bofs;

    // ---- zero halo rows (0..5, 230..235) in both buffers, once ----
    if (tid < 192) {
        int bufi = tid / 96;
        int q    = tid - 96 * bufi;
        int rr   = q >> 3;                       // 0..11
        int slot = q & 7;
        int row  = (rr < 6) ? rr : (224 + rr);   // 0..5, 230..235
        *reinterpret_cast<float4*>(&lds[bufi * BUFW + row * LDW + slot * 4]) =
            make_float4(0.f, 0.f, 0.f, 0.f);
    }

    // stage/store lane mapping: chunk i covers channels rowbase+8i (8 rows x 8 tq)
    const int srow = l >> 3;         // row within 8-row chunk
    const int stq  = l & 7;          // t-quad
    const int rowbase = 56 * w + srow;

    // ---- issue tile-0 loads (latency hidden under gaussian-kernel math) ----
    float4 vst[7];
#pragma unroll
    for (int i = 0; i < 7; ++i)
        vst[i] = *reinterpret_cast<const float4*>(
            xb + (rowbase + 8 * i) * Tt + 4 * stq);

    // ---- gaussian kernel (arithmetic identical to verified rounds 1-8) ----
    float kr[13];
    {
        float wv = wp[0];
        float wc = fminf(fmaxf(wv, 0.4f), 10.0f);
        float norm = 0.0f;
        const float step = 120.0f / 129.0f;
        for (int j = 0; j < 130; ++j) {
            float r = -60.0f + (float)j * step;
            float z = r / wc;
            norm += expf(-0.5f * z * z);
        }
        for (int i = 0; i < 13; ++i) {
            float r = (float)(i - 6);
            float z = r / wc;
            kr[i] = expf(-0.5f * z * z) / norm;
        }
    }

    // ---- write tile-0 into buf0; issue tile-1 loads ----
#pragma unroll
    for (int i = 0; i < 7; ++i)
        *reinterpret_cast<float4*>(
            &lds[(rowbase + 8 * i + 6) * LDW + 4 * stq]) = vst[i];
#pragma unroll
    for (int i = 0; i < 7; ++i)
        vst[i] = *reinterpret_cast<const float4*>(
            xb + (rowbase + 8 * i) * Tt + TT + 4 * stq);

    asm volatile("s_waitcnt lgkmcnt(0)" ::: "memory");
    __builtin_amdgcn_s_barrier();
    __builtin_amdgcn_sched_barrier(0);

    float mem = 0.f, rstv = 0.f;     // LIF state, carried across tiles
    int bufc = 0;

#pragma unroll 1
    for (int tile = 0; tile < NT; ++tile) {
        float* cur = &lds[bufc * BUFW];
        float* nxt = &lds[(bufc ^ 1) * BUFW];

        // ---- conv + LIF: 13 immediate-offset ds_read_b128 per quad ----
        unsigned m = 0;
        if (tid < Cc) {
            const float* base = cur + tid * LDW;   // rows tid..tid+12
#pragma unroll
            for (int tq = 0; tq < 8; ++tq) {
                float4 v[13];
#pragma unroll
                for (int k = 0; k < 13; ++k)
                    v[k] = *reinterpret_cast<const float4*>(base + k * LDW + 4 * tq);
                float4 acc = make_float4(0.f, 0.f, 0.f, 0.f);
#pragma unroll
                for (int k = 0; k < 13; ++k) {
                    float kk = kr[k];
                    acc.x += kk * v[k].x;  acc.y += kk * v[k].y;
                    acc.z += kk * v[k].z;  acc.w += kk * v[k].w;
                }
                const float* xv = (const float*)&v[6];   // center = own channel
                const float* av = (const float*)&acc;
#pragma unroll
                for (int s = 0; s < 4; ++s) {
                    float d  = xv[s] - av[s];
                    float rl = d > 0.0f ? d : 0.0f;
                    float I  = xv[s] - rl;               // I = x - relu(x - mean)
                    mem = 0.97f * mem + I - rstv;
                    bool sp = mem > 1.0f;
                    rstv = sp ? 1.0f : 0.0f;
                    m |= sp ? (1u << (4 * tq + s)) : 0u;
                }
            }
        }

        // ---- publish this tile's mask (parity bank breaks cross-tile races) ----
        msk[(tile & 1) * 256 + tid] = m;

        // ---- stage next tile: write regs (tile+1) into nxt, load tile+2 ----
        if (tile < NT - 1) {
#pragma unroll
            for (int i = 0; i < 7; ++i)
                *reinterpret_cast<float4*>(
                    &nxt[(rowbase + 8 * i + 6) * LDW + 4 * stq]) = vst[i];
        }
        if (tile < NT - 2) {
            const float* src = xb + (tile + 2) * TT + 4 * stq;
#pragma unroll
            for (int i = 0; i < 7; ++i)
                vst[i] = *reinterpret_cast<const float4*>(
                    src + (rowbase + 8 * i) * Tt);
        }

        asm volatile("s_waitcnt lgkmcnt(0)" ::: "memory");
        __builtin_amdgcn_s_barrier();   // masks + next-tile x visible
        __builtin_amdgcn_sched_barrier(0);

        // ---- per-tile store: 8 full 128B lines per instruction ----
        {
            const unsigned* mb = msk + (tile & 1) * 256;
            const int t0 = tile * TT;
#pragma unroll
            for (int i = 0; i < 7; ++i) {
                int cr = rowbase + 8 * i;
                unsigned rb = mb[cr] >> (4 * stq);
                float4 s4;
                s4.x = (rb & 1u) ? 1.0f : 0.0f;
                s4.y = (rb & 2u) ? 1.0f : 0.0f;
                s4.z = (rb & 4u) ? 1.0f : 0.0f;
                s4.w = (rb & 8u) ? 1.0f : 0.0f;
                *reinterpret_cast<float4*>(&ob[(long long)cr * Tt + t0 + 4 * stq]) = s4;
            }
        }

        // ---- R3-style per-tile drain: stores (and prefetch loads) retired ----
        if (tile < NT - 1) {
            asm volatile("s_waitcnt vmcnt(0)" ::: "memory");
            __builtin_amdgcn_sched_barrier(0);
        }
        bufc ^= 1;
    }
}

extern "C" void kernel_launch(void* const* d_in, const int* in_sizes, int n_in,
                              void* d_out, int out_size, void* d_ws, size_t ws_size,
                              hipStream_t stream)
{
    const float* x  = (const float*)d_in[0];
    const float* w  = (const float*)d_in[1];
    float* out      = (float*)d_out;
    const int B = in_sizes[0] / (Cc * Tt);   // 512
    cgss_snn_kernel<<<B, BDIM, 0, stream>>>(x, w, out);
}

// Round 10
// 87.204 us; speedup vs baseline: 1.0036x; 1.0036x over previous
//
#include <hip/hip_runtime.h>

constexpr int Cc   = 224;            // channels
constexpr int Tt   = 224;            // time steps
constexpr int TT   = 32;             // time tile
constexpr int NT   = Tt / TT;        // 7
constexpr int LDW  = 36;             // words per LDS row (144 B) -> b128 bank-balanced
constexpr int ROWS = 236;            // row r <-> channel r-6; rows 0..5,230..235 zero halo
constexpr int BUFW = ROWS * LDW;     // 8496 words per buffer
constexpr int BDIM = 256;

__global__ __launch_bounds__(BDIM, 2)
void cgss_snn_kernel(const float* __restrict__ x,
                     const float* __restrict__ wp,
                     float* __restrict__ out)
{
    __shared__ float lds[2 * BUFW];      // 67968 B -> 2 blocks/CU
    __shared__ unsigned msk[2][256];     // parity-banked per-tile spike masks

    const int tid = threadIdx.x;
    const int w   = tid >> 6;        // wave 0..3
    const int l   = tid & 63;
    const long long bofs = (long long)blockIdx.x * (Cc * Tt);
    const float* xb = x + bofs;
    float*       ob = out + bofs;

    // ---- zero halo rows (0..5, 230..235) in both buffers, once ----
    if (tid < 192) {
        int bufi = tid / 96;
        int q    = tid - 96 * bufi;
        int rr   = q >> 3;                       // 0..11
        int slot = q & 7;
        int row  = (rr < 6) ? rr : (224 + rr);   // 0..5, 230..235
        *reinterpret_cast<float4*>(&lds[bufi * BUFW + row * LDW + slot * 4]) =
            make_float4(0.f, 0.f, 0.f, 0.f);
    }

    // stage/store lane mapping: chunk i covers channels rowbase+8i (8 rows x 8 tq)
    const int srow = l >> 3;         // row within 8-row chunk
    const int stq  = l & 7;          // t-quad
    const int rowbase = 56 * w + srow;

    // ---- issue tile-0 loads (latency hidden under gaussian-kernel math) ----
    float4 vst[7];
#pragma unroll
    for (int i = 0; i < 7; ++i)
        vst[i] = *reinterpret_cast<const float4*>(
            xb + (rowbase + 8 * i) * Tt + 4 * stq);

    // ---- gaussian kernel (arithmetic identical to verified rounds 1-9) ----
    float kr[13];
    {
        float wv = wp[0];
        float wc = fminf(fmaxf(wv, 0.4f), 10.0f);
        float norm = 0.0f;
        const float step = 120.0f / 129.0f;
        for (int j = 0; j < 130; ++j) {
            float r = -60.0f + (float)j * step;
            float z = r / wc;
            norm += expf(-0.5f * z * z);
        }
        for (int i = 0; i < 13; ++i) {
            float r = (float)(i - 6);
            float z = r / wc;
            kr[i] = expf(-0.5f * z * z) / norm;
        }
    }

    // ---- write tile-0 into buf0; issue tile-1 loads ----
#pragma unroll
    for (int i = 0; i < 7; ++i)
        *reinterpret_cast<float4*>(
            &lds[(rowbase + 8 * i + 6) * LDW + 4 * stq]) = vst[i];
#pragma unroll
    for (int i = 0; i < 7; ++i)
        vst[i] = *reinterpret_cast<const float4*>(
            xb + (rowbase + 8 * i) * Tt + TT + 4 * stq);

    __syncthreads();                 // buf0 staged; tile-1 loads retired

    float mem = 0.f, rstv = 0.f;     // LIF state, carried across tiles
    int bufc = 0;

#pragma unroll 1
    for (int tile = 0; tile < NT; ++tile) {
        float* cur = &lds[bufc * BUFW];
        float* nxt = &lds[(bufc ^ 1) * BUFW];

        // ---- ds_write x(tile+1) into nxt (nxt free since sync of tile-1) ----
        if (tile < NT - 1) {
#pragma unroll
            for (int i = 0; i < 7; ++i)
                *reinterpret_cast<float4*>(
                    &nxt[(rowbase + 8 * i + 6) * LDW + 4 * stq]) = vst[i];
        }
        // ---- issue loads for x(tile+2): a full conv phase to cover latency ----
        if (tile < NT - 2) {
            const float* src = xb + (tile + 2) * TT + 4 * stq;
#pragma unroll
            for (int i = 0; i < 7; ++i)
                vst[i] = *reinterpret_cast<const float4*>(
                    src + (rowbase + 8 * i) * Tt);
        }

        // ---- conv + LIF: 13 immediate-offset ds_read_b128 per quad ----
        unsigned m = 0;
        if (tid < Cc) {
            const float* base = cur + tid * LDW;   // rows tid..tid+12
#pragma unroll
            for (int tq = 0; tq < 8; ++tq) {
                float4 v[13];
#pragma unroll
                for (int k = 0; k < 13; ++k)
                    v[k] = *reinterpret_cast<const float4*>(base + k * LDW + 4 * tq);
                float4 acc = make_float4(0.f, 0.f, 0.f, 0.f);
#pragma unroll
                for (int k = 0; k < 13; ++k) {
                    float kk = kr[k];
                    acc.x += kk * v[k].x;  acc.y += kk * v[k].y;
                    acc.z += kk * v[k].z;  acc.w += kk * v[k].w;
                }
                const float* xv = (const float*)&v[6];   // center = own channel
                const float* av = (const float*)&acc;
#pragma unroll
                for (int s = 0; s < 4; ++s) {
                    float d  = xv[s] - av[s];
                    float rl = d > 0.0f ? d : 0.0f;
                    float I  = xv[s] - rl;               // I = x - relu(x - mean)
                    mem = 0.97f * mem + I - rstv;
                    bool sp = mem > 1.0f;
                    rstv = sp ? 1.0f : 0.0f;
                    m |= sp ? (1u << (4 * tq + s)) : 0u;
                }
            }
        }
        msk[tile & 1][tid] = m;

        __syncthreads();             // the proven-clean drain: stores of t-1,
                                     // loads of t+2, ds_writes, msk all settled

        // ---- per-tile store: 8 full 128B lines per instruction (R3 pattern) ----
        {
            const int t0 = tile * TT;
#pragma unroll
            for (int i = 0; i < 7; ++i) {
                int cr = rowbase + 8 * i;
                unsigned rb = msk[tile & 1][cr] >> (4 * stq);
                float4 s4;
                s4.x = (rb & 1u) ? 1.0f : 0.0f;
                s4.y = (rb & 2u) ? 1.0f : 0.0f;
                s4.z = (rb & 4u) ? 1.0f : 0.0f;
                s4.w = (rb & 8u) ? 1.0f : 0.0f;
                *reinterpret_cast<float4*>(&ob[(long long)cr * Tt + t0 + 4 * stq]) = s4;
            }
        }
        bufc ^= 1;
    }
}

extern "C" void kernel_launch(void* const* d_in, const int* in_sizes, int n_in,
                              void* d_out, int out_size, void* d_ws, size_t ws_size,
                              hipStream_t stream)
{
    const float* x  = (const float*)d_in[0];
    const float* w  = (const float*)d_in[1];
    float* out      = (float*)d_out;
    const int B = in_sizes[0] / (Cc * Tt);   // 512
    cgss_snn_kernel<<<B, BDIM, 0, stream>>>(x, w, out);
}